// Round 10
// baseline (650.037 us; speedup 1.0000x reference)
//
#include <hip/hip_runtime.h>
#include <math.h>

// Problem constants
static constexpr int NB  = 64;     // batch
static constexpr int L0  = 8192;   // input length
static constexpr int L1  = 4096;   // after ec1
static constexpr int LQ  = 2048;   // latent length
static constexpr int CH  = 128;    // hidden H
static constexpr int CHH = 64;     // H/2
static constexpr int CR  = 32;     // residual hidden
static constexpr int CD  = 64;     // codebook dim D
static constexpr int NK  = 512;    // codebook size K
static constexpr int NROWS = NB * LQ;  // 131072 latent vectors

using short8 = __attribute__((ext_vector_type(8))) short;
using f32x4  = __attribute__((ext_vector_type(4))) float;

__device__ inline f32x4 mfma16(short8 a, short8 b, f32x4 c) {
    return __builtin_amdgcn_mfma_f32_16x16x32_bf16(a, b, c, 0, 0, 0);
}

__device__ inline unsigned short bf16rne(float v) {
    unsigned int bb = __builtin_bit_cast(unsigned int, v);
    unsigned int r = (bb + 0x7FFFu + ((bb >> 16) & 1u)) >> 16;
    return (unsigned short)r;
}
__device__ inline float bf2f(unsigned short s) {
    unsigned int u = ((unsigned int)s) << 16;
    return __builtin_bit_cast(float, u);
}

// ---- conv weight->fragment prep: dst [tap][cb][kb][cl*32+hi*8+j] bf16 ----
__global__ __launch_bounds__(256) void k_wtf(const float* __restrict__ src,
                                             short* __restrict__ dst,
                                             int CO, int CI, int K, int iok) {
    int i = blockIdx.x * 256 + threadIdx.x;
    int total = K * CO * CI;
    if (i >= total) return;
    int j  = i & 7;
    int hi = (i >> 3) & 3;
    int cl = (i >> 5) & 15;
    int rest = i >> 9;
    int CIb = CI >> 5, COb = CO >> 4;
    int kb = rest % CIb; rest /= CIb;
    int cb = rest % COb;
    int tap = rest / COb;
    int co = cb * 16 + cl, ci = kb * 32 + hi * 8 + j;
    float v = iok ? src[(ci * CO + co) * K + tap] : src[(co * CI + ci) * K + tap];
    dst[i] = (short)bf16rne(v);
}

// ---- k=1 weight frag prep with hi/lo split: CO=128, CI=32 ----
__global__ __launch_bounds__(256) void k_w2f(const float* __restrict__ src,
                                             short* __restrict__ hi_dst,
                                             short* __restrict__ lo_dst) {
    int i = blockIdx.x * 256 + threadIdx.x;   // 4096
    if (i >= CH * CR) return;
    int j  = i & 7;
    int hi = (i >> 3) & 3;
    int cl = (i >> 5) & 15;
    int cb = i >> 9;
    int co = cb * 16 + cl, ci = hi * 8 + j;
    float v = src[co * CR + ci];
    unsigned short h = bf16rne(v);
    hi_dst[i] = (short)h;
    lo_dst[i] = (short)bf16rne(v - bf2f(h));
}

// ---- pvq weight frag prep with hi/lo split: CO=64 (d), CI=128 ----
__global__ __launch_bounds__(256) void k_pwf(const float* __restrict__ src,
                                             short* __restrict__ hi_dst,
                                             short* __restrict__ lo_dst) {
    int i = blockIdx.x * 256 + threadIdx.x;   // 8192
    if (i >= CD * CH) return;
    int j  = i & 7;
    int hi = (i >> 3) & 3;
    int cl = (i >> 5) & 15;
    int rest = i >> 9;
    int kb = rest & 3, cb = rest >> 2;
    int d = cb * 16 + cl, ci = kb * 32 + hi * 8 + j;
    float v = src[d * CH + ci];
    unsigned short h = bf16rne(v);
    hi_dst[i] = (short)h;
    lo_dst[i] = (short)bf16rne(v - bf2f(h));
}

// ---- codebook A-frag prep, split precision: -2*cb = hi + lo (both bf16) ----
__global__ __launch_bounds__(256) void k_cbf(const float* __restrict__ cb,
                                             short* __restrict__ hi_dst,
                                             short* __restrict__ lo_dst) {
    int i = blockIdx.x * 256 + threadIdx.x;   // 32768
    if (i >= NK * CD) return;
    int j    = i & 7;
    int l    = (i >> 3) & 63;
    int half = (i >> 9) & 1;
    int mt   = i >> 10;
    int cl = l & 15, hi = l >> 4;
    int m = mt * 16 + cl;
    int k = half * 32 + hi * 8 + j;
    float v = -2.f * cb[m * CD + k];
    unsigned short h = bf16rne(v);
    float r = v - bf2f(h);
    hi_dst[i] = (short)h;
    lo_dst[i] = (short)bf16rne(r);
}

// ---------------- ec1: [B,1,8192] -> [B,64,4096], k4 s2 p1, bias+ReLU ----------------
__global__ __launch_bounds__(256) void k_ec1(const float* __restrict__ x,
                                             const float* __restrict__ w,
                                             const float* __restrict__ bias,
                                             float* __restrict__ out) {
    int n = blockIdx.x * 256 + threadIdx.x;
    int t  = n & (L1 - 1);
    int co = (n >> 12) & (CHH - 1);
    int b  = n >> 18;
    const float* xp = x + b * L0;
    float acc = bias[co];
    int p0 = 2 * t - 1;
#pragma unroll
    for (int k = 0; k < 4; ++k) {
        int p = p0 + k;
        if (p >= 0 && p < L0) acc += w[co * 4 + k] * xp[p];
    }
    out[n] = fmaxf(acc, 0.f);
}

// ---------------- MFMA conv v2: bf16 swizzled LDS [t][ci], ds_read_b128 B-frags -------
template <int CIN, int COUT, int NTAPS, int TSTRIDE, int SWS, int LIN,
          bool RELU_IN, bool TRANS_IN, bool HAS_BIAS, bool RELU_OUT>
__global__ __launch_bounds__(256) void k_mfconv2(const float* __restrict__ x,
                                                 const short* __restrict__ wf,
                                                 const float* __restrict__ bias,
                                                 float* __restrict__ out) {
    constexpr int XW = 63 * TSTRIDE + NTAPS;
    constexpr int MR = (COUT == 128) ? 4 : 1;
    constexpr int COb = COUT / 16, CIb = CIN / 32;
    __shared__ unsigned int xsu[CIN * XW / 2];
    int t0 = blockIdx.x * 64;
    int b  = blockIdx.z;
    int tid = threadIdx.x;

    if (TRANS_IN) {
        for (int i = tid; i < XW * (CIN / 2); i += 256) {
            int j = i / (CIN / 2);
            int ci = (i - j * (CIN / 2)) * 2;
            int p = t0 - 1 + j;
            float vx = 0.f, vy = 0.f;
            if (p >= 0 && p < LIN) {
                const float* s = x + ((size_t)b * LIN + p) * CIN + ci;
                vx = s[0]; vy = s[1];
            }
            if (RELU_IN) { vx = fmaxf(vx, 0.f); vy = fmaxf(vy, 0.f); }
            unsigned int u = (__builtin_bit_cast(unsigned int, vx) >> 16)
                           | (__builtin_bit_cast(unsigned int, vy) & 0xFFFF0000u);
            int byte = (j * CIN + ci) * 2;
            byte ^= ((j >> SWS) & 7) << 4;
            xsu[byte >> 2] = u;
        }
    } else {
        for (int i = tid; i < (CIN / 2) * XW; i += 256) {
            int ci2 = i / XW;
            int j = i - ci2 * XW;
            int ci = ci2 * 2;
            int p = t0 * TSTRIDE - 1 + j;
            float vx = 0.f, vy = 0.f;
            if (p >= 0 && p < LIN) {
                const float* s = x + ((size_t)b * CIN + ci) * LIN + p;
                vx = s[0]; vy = s[LIN];
            }
            if (RELU_IN) { vx = fmaxf(vx, 0.f); vy = fmaxf(vy, 0.f); }
            unsigned int u = (__builtin_bit_cast(unsigned int, vx) >> 16)
                           | (__builtin_bit_cast(unsigned int, vy) & 0xFFFF0000u);
            int byte = (j * CIN + ci) * 2;
            byte ^= ((j >> SWS) & 7) << 4;
            xsu[byte >> 2] = u;
        }
    }
    __syncthreads();

    int l  = tid & 63;
    int w  = tid >> 6;
    int cl = l & 15, hi = l >> 4;
    int co_w = (w & 1) * (MR * 16);
    int t_w  = (w >> 1) * 32;

    f32x4 acc[MR][2];
#pragma unroll
    for (int m = 0; m < MR; ++m)
#pragma unroll
        for (int n = 0; n < 2; ++n) acc[m][n] = (f32x4){0.f, 0.f, 0.f, 0.f};

#pragma unroll
    for (int tap = 0; tap < NTAPS; ++tap) {
#pragma unroll
        for (int kb = 0; kb < CIb; ++kb) {
            const short* ap = wf + ((size_t)((tap * COb + co_w / 16) * CIb + kb)) * 512
                            + cl * 32 + hi * 8;
            short8 a[MR];
#pragma unroll
            for (int m = 0; m < MR; ++m)
                a[m] = *reinterpret_cast<const short8*>(ap + (size_t)m * CIb * 512);
            short8 bf[2];
#pragma unroll
            for (int n = 0; n < 2; ++n) {
                int tt = (t_w + n * 16 + cl) * TSTRIDE + tap;
                int byte = (tt * CIN + kb * 32 + hi * 8) * 2;
                byte ^= ((tt >> SWS) & 7) << 4;
                bf[n] = *reinterpret_cast<const short8*>(
                            reinterpret_cast<const char*>(xsu) + byte);
            }
#pragma unroll
            for (int m = 0; m < MR; ++m)
#pragma unroll
                for (int n = 0; n < 2; ++n)
                    acc[m][n] = mfma16(a[m], bf[n], acc[m][n]);
        }
    }

#pragma unroll
    for (int m = 0; m < MR; ++m) {
#pragma unroll
        for (int n = 0; n < 2; ++n) {
#pragma unroll
            for (int r = 0; r < 4; ++r) {
                int co = co_w + m * 16 + hi * 4 + r;
                int t  = t0 + t_w + n * 16 + cl;
                float v = acc[m][n][r];
                if (HAS_BIAS) v += bias[co];
                if (RELU_OUT) v = fmaxf(v, 0.f);
                out[((size_t)b * COUT + co) * LQ + t] = v;
            }
        }
    }
}

// ---------------- dc1 with codebook gather: in = cb[idx[p]], k3 p1, bias ----------------
__global__ __launch_bounds__(256) void k_dc1g(const int* __restrict__ idx,
                                              const float* __restrict__ cb,
                                              const short* __restrict__ wf,
                                              const float* __restrict__ bias,
                                              float* __restrict__ out) {
    constexpr int XW = 66;
    __shared__ unsigned int xsu[CD * XW / 2];
    int t0 = blockIdx.x * 64;
    int b  = blockIdx.z;
    int tid = threadIdx.x;

    for (int i = tid; i < XW * (CD / 2); i += 256) {
        int j = i >> 5;                  // /(CD/2)=32
        int ci = (i & 31) * 2;
        int p = t0 - 1 + j;
        float vx = 0.f, vy = 0.f;
        if (p >= 0 && p < LQ) {
            int id = idx[(size_t)b * LQ + p];
            const float* s = cb + (size_t)id * CD + ci;
            vx = s[0]; vy = s[1];
        }
        unsigned int u = (__builtin_bit_cast(unsigned int, vx) >> 16)
                       | (__builtin_bit_cast(unsigned int, vy) & 0xFFFF0000u);
        int byte = (j * CD + ci) * 2;
        byte ^= (j & 7) << 4;
        xsu[byte >> 2] = u;
    }
    __syncthreads();

    int l  = tid & 63;
    int w  = tid >> 6;
    int cl = l & 15, hi = l >> 4;
    int co_w = (w & 1) * 64;
    int t_w  = (w >> 1) * 32;

    f32x4 acc[4][2];
#pragma unroll
    for (int m = 0; m < 4; ++m)
#pragma unroll
        for (int n = 0; n < 2; ++n) acc[m][n] = (f32x4){0.f, 0.f, 0.f, 0.f};

#pragma unroll
    for (int tap = 0; tap < 3; ++tap) {
#pragma unroll
        for (int kb = 0; kb < 2; ++kb) {
            const short* ap = wf + ((size_t)((tap * 8 + co_w / 16) * 2 + kb)) * 512
                            + cl * 32 + hi * 8;
            short8 a[4];
#pragma unroll
            for (int m = 0; m < 4; ++m)
                a[m] = *reinterpret_cast<const short8*>(ap + (size_t)m * 2 * 512);
            short8 bf[2];
#pragma unroll
            for (int n = 0; n < 2; ++n) {
                int tt = (t_w + n * 16 + cl) + tap;
                int byte = (tt * CD + kb * 32 + hi * 8) * 2;
                byte ^= (tt & 7) << 4;
                bf[n] = *reinterpret_cast<const short8*>(
                            reinterpret_cast<const char*>(xsu) + byte);
            }
#pragma unroll
            for (int m = 0; m < 4; ++m)
#pragma unroll
                for (int n = 0; n < 2; ++n)
                    acc[m][n] = mfma16(a[m], bf[n], acc[m][n]);
        }
    }

#pragma unroll
    for (int m = 0; m < 4; ++m) {
#pragma unroll
        for (int n = 0; n < 2; ++n) {
#pragma unroll
            for (int r = 0; r < 4; ++r) {
                int co = co_w + m * 16 + hi * 4 + r;
                int t  = t0 + t_w + n * 16 + cl;
                out[((size_t)b * CH + co) * LQ + t] = acc[m][n][r] + bias[co];
            }
        }
    }
}

// ---------------- fused residual block: dst = src + W2 . relu(conv3(relu(src))) --------
__global__ __launch_bounds__(256) void k_resblk(const float* __restrict__ src,
                                                float* __restrict__ dst,
                                                const short* __restrict__ wf1,
                                                const short* __restrict__ w2h,
                                                const short* __restrict__ w2l) {
    constexpr int XW = 66;
    __shared__ unsigned int xsu[CH * XW / 2];   // 16896 B
    __shared__ unsigned int hh[64 * 16];        // [t][ciu] hi, 4 KB
    __shared__ unsigned int hl[64 * 16];        // lo, 4 KB
    int t0 = blockIdx.x * 64;
    int b  = blockIdx.z;
    int tid = threadIdx.x;

    for (int i = tid; i < (CH / 2) * XW; i += 256) {
        int ci2 = i / XW;
        int j = i - ci2 * XW;
        int ci = ci2 * 2;
        int p = t0 - 1 + j;
        float vx = 0.f, vy = 0.f;
        if (p >= 0 && p < LQ) {
            const float* s = src + ((size_t)b * CH + ci) * LQ + p;
            vx = fmaxf(s[0], 0.f); vy = fmaxf(s[LQ], 0.f);
        }
        unsigned int u = (__builtin_bit_cast(unsigned int, vx) >> 16)
                       | (__builtin_bit_cast(unsigned int, vy) & 0xFFFF0000u);
        int byte = (j * CH + ci) * 2;
        byte ^= (j & 7) << 4;
        xsu[byte >> 2] = u;
    }
    __syncthreads();

    int l  = tid & 63;
    int w  = tid >> 6;
    int cl = l & 15, hi = l >> 4;
    int co_w1 = (w & 1) * 16;     // h-channel tile base (0 or 16)
    int t_w   = (w >> 1) * 32;    // t base (0..32)

    // ---- stage 1: h = conv3(relu(x)) ----
    f32x4 acc1[2];
    acc1[0] = (f32x4){0.f, 0.f, 0.f, 0.f};
    acc1[1] = (f32x4){0.f, 0.f, 0.f, 0.f};
#pragma unroll
    for (int tap = 0; tap < 3; ++tap) {
#pragma unroll
        for (int kb = 0; kb < 4; ++kb) {
            const short* ap = wf1 + ((size_t)((tap * 2 + (w & 1)) * 4 + kb)) * 512
                            + cl * 32 + hi * 8;
            short8 a = *reinterpret_cast<const short8*>(ap);
#pragma unroll
            for (int n = 0; n < 2; ++n) {
                int tt = (t_w + n * 16 + cl) + tap;
                int byte = (tt * CH + kb * 32 + hi * 8) * 2;
                byte ^= (tt & 7) << 4;
                short8 bf = *reinterpret_cast<const short8*>(
                                reinterpret_cast<const char*>(xsu) + byte);
                acc1[n] = mfma16(a, bf, acc1[n]);
            }
        }
    }

    // relu + hi/lo split -> h LDS [t][ciu] (u32 = 2 bf16), swizzle idx ^= (t&3)<<2
#pragma unroll
    for (int n = 0; n < 2; ++n) {
        int t = t_w + n * 16 + cl;
#pragma unroll
        for (int rp = 0; rp < 2; ++rp) {
            float v0 = fmaxf(acc1[n][2 * rp], 0.f);
            float v1 = fmaxf(acc1[n][2 * rp + 1], 0.f);
            unsigned short h0 = bf16rne(v0), h1 = bf16rne(v1);
            unsigned short l0 = bf16rne(v0 - bf2f(h0)), l1 = bf16rne(v1 - bf2f(h1));
            int ciu = (co_w1 >> 1) + hi * 2 + rp;
            int idx = t * 16 + (ciu ^ ((t & 3) << 2));
            hh[idx] = (unsigned int)h0 | ((unsigned int)h1 << 16);
            hl[idx] = (unsigned int)l0 | ((unsigned int)l1 << 16);
        }
    }
    __syncthreads();

    // ---- stage 2: res = W2 . relu(h), split precision; dst = src + res ----
    int co2_w = (w & 1) * 64;
    short8 bh[2], bl[2];
#pragma unroll
    for (int n2 = 0; n2 < 2; ++n2) {
        int t = t_w + n2 * 16 + cl;
        int idx = t * 16 + ((hi * 4) ^ ((t & 3) << 2));
        bh[n2] = *reinterpret_cast<const short8*>(&hh[idx]);
        bl[n2] = *reinterpret_cast<const short8*>(&hl[idx]);
    }
#pragma unroll
    for (int m2 = 0; m2 < 4; ++m2) {
        int co2 = co2_w + m2 * 16;
        const short* aph = w2h + (co2 / 16) * 512 + cl * 32 + hi * 8;
        const short* apl = w2l + (co2 / 16) * 512 + cl * 32 + hi * 8;
        short8 ah = *reinterpret_cast<const short8*>(aph);
        short8 al = *reinterpret_cast<const short8*>(apl);
#pragma unroll
        for (int n2 = 0; n2 < 2; ++n2) {
            f32x4 acc = (f32x4){0.f, 0.f, 0.f, 0.f};
            acc = mfma16(ah, bl[n2], acc);
            acc = mfma16(al, bh[n2], acc);
            acc = mfma16(ah, bh[n2], acc);
            int t = t0 + t_w + n2 * 16 + cl;
#pragma unroll
            for (int r = 0; r < 4; ++r) {
                int co = co2 + hi * 4 + r;
                size_t off = ((size_t)b * CH + co) * LQ + t;
                dst[off] = src[off] + acc[r];
            }
        }
    }
}

// ---------------- dt1 MFMA v2: ConvT 128->64 k4 s2 p1, relu(in), relu(out) -------------
__global__ __launch_bounds__(256) void k_dt1m(const float* __restrict__ x,
                                              const short* __restrict__ wf,  // IOK frags
                                              const float* __restrict__ bias,
                                              float* __restrict__ out) {
    constexpr int XW = 66;
    __shared__ unsigned int xsu[CH * XW / 2];
    int t0 = blockIdx.x * 64;     // u-range base
    int b  = blockIdx.z;
    int tid = threadIdx.x;
    for (int i = tid; i < (CH / 2) * XW; i += 256) {
        int ci2 = i / XW;
        int j = i - ci2 * XW;
        int ci = ci2 * 2;
        int p = t0 - 1 + j;
        float vx = 0.f, vy = 0.f;
        if (p >= 0 && p < LQ) {
            const float* s = x + ((size_t)b * CH + ci) * LQ + p;
            vx = fmaxf(s[0], 0.f); vy = fmaxf(s[LQ], 0.f);
        }
        unsigned int u = (__builtin_bit_cast(unsigned int, vx) >> 16)
                       | (__builtin_bit_cast(unsigned int, vy) & 0xFFFF0000u);
        int byte = (j * CH + ci) * 2;
        byte ^= (j & 7) << 4;
        xsu[byte >> 2] = u;
    }
    __syncthreads();

    int l  = tid & 63;
    int w  = tid >> 6;
    int cl = l & 15, hi = l >> 4;
    int co_w = (w & 1) * 32;
    int u_w  = (w >> 1) * 32;

    f32x4 ae[2][2], ao[2][2];
#pragma unroll
    for (int m = 0; m < 2; ++m)
#pragma unroll
        for (int n = 0; n < 2; ++n) {
            ae[m][n] = (f32x4){0.f, 0.f, 0.f, 0.f};
            ao[m][n] = (f32x4){0.f, 0.f, 0.f, 0.f};
        }

    const int TK[4] = {1, 3, 0, 2};
    const int TO[4] = {1, 0, 2, 1};
#pragma unroll
    for (int te = 0; te < 4; ++te) {
        int k = TK[te], off = TO[te];
#pragma unroll
        for (int kb = 0; kb < 4; ++kb) {
            const short* ap = wf + (size_t)((k * 4 + co_w / 16) * 4 + kb) * 512
                            + cl * 32 + hi * 8;
            short8 a[2];
#pragma unroll
            for (int m = 0; m < 2; ++m)
                a[m] = *reinterpret_cast<const short8*>(ap + (size_t)m * 4 * 512);
            short8 bf[2];
#pragma unroll
            for (int n = 0; n < 2; ++n) {
                int tt = u_w + n * 16 + cl + off;
                int byte = (tt * CH + kb * 32 + hi * 8) * 2;
                byte ^= (tt & 7) << 4;
                bf[n] = *reinterpret_cast<const short8*>(
                            reinterpret_cast<const char*>(xsu) + byte);
            }
#pragma unroll
            for (int m = 0; m < 2; ++m)
#pragma unroll
                for (int n = 0; n < 2; ++n) {
                    if (te < 2) ae[m][n] = mfma16(a[m], bf[n], ae[m][n]);
                    else        ao[m][n] = mfma16(a[m], bf[n], ao[m][n]);
                }
        }
    }

#pragma unroll
    for (int m = 0; m < 2; ++m) {
#pragma unroll
        for (int n = 0; n < 2; ++n) {
#pragma unroll
            for (int r = 0; r < 4; ++r) {
                int co = co_w + m * 16 + hi * 4 + r;
                int u  = t0 + u_w + n * 16 + cl;
                float bv = bias[co];
                float2 rr;
                rr.x = fmaxf(ae[m][n][r] + bv, 0.f);
                rr.y = fmaxf(ao[m][n][r] + bv, 0.f);
                *reinterpret_cast<float2*>(&out[((size_t)b * CHH + co) * L1 + 2 * u]) = rr;
            }
        }
    }
}

// ---------------- pvq via split-precision MFMA: z[b,t,d], fp32-accurate ----------------
__global__ __launch_bounds__(256) void k_pvqm(const float* __restrict__ x,
                                              const short* __restrict__ pwh,
                                              const short* __restrict__ pwl,
                                              const float* __restrict__ bias,
                                              float* __restrict__ z) {
    __shared__ unsigned int xh[(CH / 2) * 64];   // 16 KB
    __shared__ unsigned int xl[(CH / 2) * 64];   // 16 KB
    int t0 = blockIdx.x * 64;
    int b  = blockIdx.y;
    int tid = threadIdx.x;

    for (int i = tid; i < (CH / 2) * 64; i += 256) {
        int ci2 = i >> 6;
        int t = i & 63;
        int ci = ci2 * 2;
        const float* s = x + ((size_t)b * CH + ci) * LQ + t0 + t;
        float vx = fmaxf(s[0], 0.f);
        float vy = fmaxf(s[LQ], 0.f);
        unsigned short hx = bf16rne(vx), hy = bf16rne(vy);
        unsigned short lx = bf16rne(vx - bf2f(hx)), ly = bf16rne(vy - bf2f(hy));
        int byte = (t * CH + ci) * 2;
        byte ^= (t & 7) << 4;
        xh[byte >> 2] = (unsigned int)hx | ((unsigned int)hy << 16);
        xl[byte >> 2] = (unsigned int)lx | ((unsigned int)ly << 16);
    }
    __syncthreads();

    int l  = tid & 63;
    int w  = tid >> 6;                 // wave = d-tile (4 x 16 = 64 d)
    int cl = l & 15, hi = l >> 4;

    float4 bv4 = *reinterpret_cast<const float4*>(&bias[w * 16 + hi * 4]);
    f32x4 acc[4];
#pragma unroll
    for (int nt = 0; nt < 4; ++nt) acc[nt] = (f32x4){bv4.x, bv4.y, bv4.z, bv4.w};

#pragma unroll
    for (int kb = 0; kb < 4; ++kb) {
        const short* aph = pwh + ((size_t)(w * 4 + kb)) * 512 + cl * 32 + hi * 8;
        const short* apl = pwl + ((size_t)(w * 4 + kb)) * 512 + cl * 32 + hi * 8;
        short8 ah = *reinterpret_cast<const short8*>(aph);
        short8 al = *reinterpret_cast<const short8*>(apl);
#pragma unroll
        for (int nt = 0; nt < 4; ++nt) {
            int tt = nt * 16 + cl;
            int byte = (tt * CH + kb * 32 + hi * 8) * 2;
            byte ^= (tt & 7) << 4;
            short8 bhf = *reinterpret_cast<const short8*>(
                             reinterpret_cast<const char*>(xh) + byte);
            short8 blf = *reinterpret_cast<const short8*>(
                             reinterpret_cast<const char*>(xl) + byte);
            acc[nt] = mfma16(ah, blf, acc[nt]);
            acc[nt] = mfma16(al, bhf, acc[nt]);
            acc[nt] = mfma16(ah, bhf, acc[nt]);
        }
    }

#pragma unroll
    for (int nt = 0; nt < 4; ++nt) {
        int t = t0 + nt * 16 + cl;
        float4 o;
        o.x = acc[nt][0]; o.y = acc[nt][1]; o.z = acc[nt][2]; o.w = acc[nt][3];
        *reinterpret_cast<float4*>(&z[((size_t)b * LQ + t) * CD + w * 16 + hi * 4]) = o;
    }
}

// ---------------- cb2[k] = |codebook_k|^2 ----------------
__global__ __launch_bounds__(256) void k_cb2(const float* __restrict__ cb,
                                             float* __restrict__ cb2) {
    int k = blockIdx.x * 256 + threadIdx.x;
    if (k >= NK) return;
    const float* r = cb + k * CD;
    float s = 0.f;
#pragma unroll 8
    for (int i = 0; i < CD; ++i) s += r[i] * r[i];
    cb2[k] = s;
}

// ---------------- VQ v3: LDS-staged codebook frags, 128 rows/block ----------------
// grid 1024 (4 blocks/CU), 36 KB LDS. scores = |c|^2 - 2 z.c, split precision.
__global__ __launch_bounds__(256) void k_vqm(const float* __restrict__ z,
                                             const short* __restrict__ cbf_hi,
                                             const short* __restrict__ cbf_lo,
                                             const float* __restrict__ cb2,
                                             const float* __restrict__ cb,
                                             int* __restrict__ idxout,
                                             int* __restrict__ counts,
                                             float* __restrict__ sse) {
    __shared__ short cbh_l[8192];     // 8 mt tiles (hi), 16 KB
    __shared__ short cbl_l[8192];     // 8 mt tiles (lo), 16 KB
    __shared__ float c2l[NK];         // 2 KB
    __shared__ int   hist[NK];        // 2 KB
    int tid = threadIdx.x;
    int l   = tid & 63;
    int w   = tid >> 6;
    int cl  = l & 15, hi = l >> 4;
    int wrow0 = blockIdx.x * 128 + w * 32;

    for (int i = tid; i < NK; i += 256) { c2l[i] = cb2[i]; hist[i] = 0; }

    // load z fragments (2 row-tiles of 16), split hi/lo (RNE)
    short8 bh[2][2], bl[2][2];
#pragma unroll
    for (int nt = 0; nt < 2; ++nt) {
        int row = wrow0 + nt * 16 + cl;
        const float* zr = z + (size_t)row * CD;
#pragma unroll
        for (int half = 0; half < 2; ++half) {
            const float4* p4 = reinterpret_cast<const float4*>(zr + half * 32 + hi * 8);
            float4 v0 = p4[0], v1 = p4[1];
            float vs[8] = {v0.x, v0.y, v0.z, v0.w, v1.x, v1.y, v1.z, v1.w};
            short8 sh, sl;
#pragma unroll
            for (int j = 0; j < 8; ++j) {
                unsigned short h = bf16rne(vs[j]);
                float r = vs[j] - bf2f(h);
                sh[j] = (short)h;
                sl[j] = (short)bf16rne(r);
            }
            bh[nt][half] = sh;
            bl[nt][half] = sl;
        }
    }

    float bscore[2];
    int   bidx[2];
#pragma unroll
    for (int nt = 0; nt < 2; ++nt) { bscore[nt] = 1e30f; bidx[nt] = 0; }

    for (int ch = 0; ch < 4; ++ch) {
        __syncthreads();
        {
            const float4* srch = reinterpret_cast<const float4*>(cbf_hi + ch * 8192);
            const float4* srcl = reinterpret_cast<const float4*>(cbf_lo + ch * 8192);
            float4* dsth = reinterpret_cast<float4*>(cbh_l);
            float4* dstl = reinterpret_cast<float4*>(cbl_l);
            for (int i = tid; i < 1024; i += 256) { dsth[i] = srch[i]; dstl[i] = srcl[i]; }
        }
        __syncthreads();
#pragma unroll
        for (int mtl = 0; mtl < 8; ++mtl) {
            int mt = ch * 8 + mtl;
            short8 ah0 = *reinterpret_cast<const short8*>(&cbh_l[(mtl * 2 + 0) * 512 + l * 8]);
            short8 ah1 = *reinterpret_cast<const short8*>(&cbh_l[(mtl * 2 + 1) * 512 + l * 8]);
            short8 al0 = *reinterpret_cast<const short8*>(&cbl_l[(mtl * 2 + 0) * 512 + l * 8]);
            short8 al1 = *reinterpret_cast<const short8*>(&cbl_l[(mtl * 2 + 1) * 512 + l * 8]);
            float4 c2v = *reinterpret_cast<const float4*>(&c2l[mt * 16 + hi * 4]);
            f32x4 cin = (f32x4){c2v.x, c2v.y, c2v.z, c2v.w};
            int mbase = mt * 16 + hi * 4;
#pragma unroll
            for (int nt = 0; nt < 2; ++nt) {
                f32x4 acc = mfma16(al0, bh[nt][0], cin);    // A_lo . z_hi
                acc = mfma16(al1, bh[nt][1], acc);
                acc = mfma16(ah0, bl[nt][0], acc);          // A_hi . z_lo
                acc = mfma16(ah1, bl[nt][1], acc);
                acc = mfma16(ah0, bh[nt][0], acc);          // A_hi . z_hi
                acc = mfma16(ah1, bh[nt][1], acc);
#pragma unroll
                for (int r = 0; r < 4; ++r) {
                    float s = acc[r];
                    bool better = s < bscore[nt];
                    bscore[nt] = better ? s : bscore[nt];
                    bidx[nt]   = better ? (mbase + r) : bidx[nt];
                }
            }
        }
    }

    // cross-lane argmin + fused epilogue (idx write, SSE, hist)
    float err = 0.f;
#pragma unroll
    for (int nt = 0; nt < 2; ++nt) {
        float s = bscore[nt];
        int   id = bidx[nt];
#pragma unroll
        for (int off = 16; off <= 32; off <<= 1) {
            float s2 = __shfl_xor(s, off);
            int   i2 = __shfl_xor(id, off);
            bool take = (s2 < s) || (s2 == s && i2 < id);
            s  = take ? s2 : s;
            id = take ? i2 : id;
        }
        int row = wrow0 + nt * 16 + cl;
        if (hi == 0) idxout[row] = id;
        const float4* cbr = reinterpret_cast<const float4*>(cb + (size_t)id * CD);
        float4 q0 = cbr[hi * 2];
        float4 q1 = cbr[hi * 2 + 1];
        float4 q2 = cbr[8 + hi * 2];
        float4 q3 = cbr[8 + hi * 2 + 1];
        float qv[16] = {q0.x, q0.y, q0.z, q0.w, q1.x, q1.y, q1.z, q1.w,
                        q2.x, q2.y, q2.z, q2.w, q3.x, q3.y, q3.z, q3.w};
#pragma unroll
        for (int half = 0; half < 2; ++half) {
#pragma unroll
            for (int j = 0; j < 8; ++j) {
                float zv = bf2f((unsigned short)bh[nt][half][j])
                         + bf2f((unsigned short)bl[nt][half][j]);
                float d = qv[half * 8 + j] - zv;
                err = fmaf(d, d, err);
            }
        }
        if (hi == 0) atomicAdd(&hist[id], 1);
    }
#pragma unroll
    for (int s = 32; s > 0; s >>= 1) err += __shfl_xor(err, s);
    if (l == 0) atomicAdd(sse, err);

    __syncthreads();
    for (int i = tid; i < NK; i += 256) {
        int h = hist[i];
        if (h) atomicAdd(&counts[i], h);
    }
}

// ---------------- dt2: ConvT 64->1 k4 s2 p1 -> recon ----------------
__global__ __launch_bounds__(256) void k_dt2(const float* __restrict__ x,
                                             const float* __restrict__ w,
                                             const float* __restrict__ bias,
                                             float* __restrict__ out) {
    int u = blockIdx.x * 256 + threadIdx.x;
    int b = blockIdx.y;
    const float* xp = x + (size_t)b * CHH * L1 + u;
    float bv = bias[0];
    float ae = bv, ao = bv;
    for (int ci = 0; ci < CHH; ++ci) {
        const float* xr = xp + ci * L1;
        float xm  = (u >= 1) ? xr[-1] : 0.f;
        float x0  = xr[0];
        float xp1 = (u < L1 - 1) ? xr[1] : 0.f;
        const float* wc = w + ci * 4;
        ae += wc[1] * x0 + wc[3] * xm;
        ao += wc[0] * xp1 + wc[2] * x0;
    }
    reinterpret_cast<float2*>(out + (size_t)b * L0)[u] = make_float2(ae, ao);
}

// ---------------- finalize: vq_loss + perplexity ----------------
__global__ __launch_bounds__(512) void k_final(const int* __restrict__ counts,
                                               const float* __restrict__ sse,
                                               float* __restrict__ out) {
    __shared__ float red[8];
    int tid = threadIdx.x;
    float p = (float)counts[tid] * (1.f / (float)NROWS);
    float v = p * logf(p + 1e-10f);
#pragma unroll
    for (int s = 32; s > 0; s >>= 1) v += __shfl_down(v, s);
    if ((tid & 63) == 0) red[tid >> 6] = v;
    __syncthreads();
    if (tid == 0) {
        float tot = 0.f;
        for (int i = 0; i < 8; ++i) tot += red[i];
        out[524288] = 1.25f * sse[0] / ((float)NROWS * (float)CD);
        out[524289] = expf(-tot);
    }
}

extern "C" void kernel_launch(void* const* d_in, const int* in_sizes, int n_in,
                              void* d_out, int out_size, void* d_ws, size_t ws_size,
                              hipStream_t stream) {
    const float* x      = (const float*)d_in[0];
    const float* ec1_w  = (const float*)d_in[1];
    const float* ec1_b  = (const float*)d_in[2];
    const float* ec2_w  = (const float*)d_in[3];
    const float* ec2_b  = (const float*)d_in[4];
    const float* ec3_w  = (const float*)d_in[5];
    const float* ec3_b  = (const float*)d_in[6];
    const float* er1_w1 = (const float*)d_in[7];
    const float* er1_w2 = (const float*)d_in[8];
    const float* er2_w1 = (const float*)d_in[9];
    const float* er2_w2 = (const float*)d_in[10];
    const float* pvq_w  = (const float*)d_in[11];
    const float* pvq_b  = (const float*)d_in[12];
    const float* cbk    = (const float*)d_in[13];
    const float* dc1_w  = (const float*)d_in[14];
    const float* dc1_b  = (const float*)d_in[15];
    const float* dr1_w1 = (const float*)d_in[16];
    const float* dr1_w2 = (const float*)d_in[17];
    const float* dr2_w1 = (const float*)d_in[18];
    const float* dr2_w2 = (const float*)d_in[19];
    const float* dt1_w  = (const float*)d_in[20];
    const float* dt1_b  = (const float*)d_in[21];
    const float* dt2_w  = (const float*)d_in[22];
    const float* dt2_b  = (const float*)d_in[23];
    float* out = (float*)d_out;

    char* ws = (char*)d_ws;
    float* A    = (float*)(ws);                        // 64 MB
    float* Bb   = (float*)(ws + 67108864);             // 64 MB
    char*  smal = ws + 134217728;
    int*   counts = (int*)smal;                        // 2048 B
    float* sse    = (float*)(smal + 2048);             // 4 B
    float* cb2    = (float*)(smal + 4096);             // 2048 B
    short* wf_ec2 = (short*)(smal + 8192);             // 32768 sh
    short* wf_ec3 = wf_ec2 + 32768;                    // 49152 sh
    short* wf_er1 = wf_ec3 + 49152;                    // 12288 sh
    short* wf_er2 = wf_er1 + 12288;
    short* wf_dc1 = wf_er2 + 12288;                    // 24576 sh
    short* wf_dr1 = wf_dc1 + 24576;
    short* wf_dr2 = wf_dr1 + 12288;
    short* wf_dt1 = wf_dr2 + 12288;                    // 32768 sh
    short* cbf_hi = wf_dt1 + 32768;                    // 32768 sh
    short* cbf_lo = cbf_hi + 32768;                    // 32768 sh
    short* w2_er1h = cbf_lo + 32768;                   // 4096 sh each
    short* w2_er1l = w2_er1h + 4096;
    short* w2_er2h = w2_er1l + 4096;
    short* w2_er2l = w2_er2h + 4096;
    short* w2_dr1h = w2_er2l + 4096;
    short* w2_dr1l = w2_dr1h + 4096;
    short* w2_dr2h = w2_dr1l + 4096;
    short* w2_dr2l = w2_dr2h + 4096;
    short* pw_hi   = w2_dr2l + 4096;                   // 8192 sh
    short* pw_lo   = pw_hi + 8192;                     // 8192 sh
    float* z = Bb;                                     // 32 MB  [B,2048,64]
    int*   idxv = (int*)((char*)Bb + 33554432);        // 512 KB (dead after dc1)

    hipMemsetAsync(smal, 0, 2056, stream);

    // weight / codebook fragment prep (tiny)
    k_wtf<<<dim3(128), 256, 0, stream>>>(ec2_w, wf_ec2, 128, 64, 4, 0);
    k_wtf<<<dim3(192), 256, 0, stream>>>(ec3_w, wf_ec3, 128, 128, 3, 0);
    k_wtf<<<dim3(48), 256, 0, stream>>>(er1_w1, wf_er1, 32, 128, 3, 0);
    k_wtf<<<dim3(48), 256, 0, stream>>>(er2_w1, wf_er2, 32, 128, 3, 0);
    k_wtf<<<dim3(96), 256, 0, stream>>>(dc1_w, wf_dc1, 128, 64, 3, 0);
    k_wtf<<<dim3(48), 256, 0, stream>>>(dr1_w1, wf_dr1, 32, 128, 3, 0);
    k_wtf<<<dim3(48), 256, 0, stream>>>(dr2_w1, wf_dr2, 32, 128, 3, 0);
    k_wtf<<<dim3(128), 256, 0, stream>>>(dt1_w, wf_dt1, 64, 128, 4, 1);
    k_w2f<<<dim3(16), 256, 0, stream>>>(er1_w2, w2_er1h, w2_er1l);
    k_w2f<<<dim3(16), 256, 0, stream>>>(er2_w2, w2_er2h, w2_er2l);
    k_w2f<<<dim3(16), 256, 0, stream>>>(dr1_w2, w2_dr1h, w2_dr1l);
    k_w2f<<<dim3(16), 256, 0, stream>>>(dr2_w2, w2_dr2h, w2_dr2l);
    k_pwf<<<dim3(32), 256, 0, stream>>>(pvq_w, pw_hi, pw_lo);
    k_cbf<<<dim3(128), 256, 0, stream>>>(cbk, cbf_hi, cbf_lo);
    k_cb2<<<dim3(2), 256, 0, stream>>>(cbk, cb2);

    // encoder
    k_ec1<<<dim3((NB * CHH * L1) / 256), 256, 0, stream>>>(x, ec1_w, ec1_b, A);
    k_mfconv2<64, 128, 4, 2, 1, L1, false, false, true, true>
        <<<dim3(LQ / 64, 1, NB), 256, 0, stream>>>(A, wf_ec2, ec2_b, Bb);
    k_mfconv2<128, 128, 3, 1, 0, LQ, false, false, true, false>
        <<<dim3(LQ / 64, 1, NB), 256, 0, stream>>>(Bb, wf_ec3, ec3_b, A);
    // fused residual blocks (ping-pong: halo read forbids in-place)
    k_resblk<<<dim3(LQ / 64, 1, NB), 256, 0, stream>>>(A, Bb, wf_er1, w2_er1h, w2_er1l);
    k_resblk<<<dim3(LQ / 64, 1, NB), 256, 0, stream>>>(Bb, A, wf_er2, w2_er2h, w2_er2l);
    k_pvqm<<<dim3(LQ / 64, NB), 256, 0, stream>>>(A, pw_hi, pw_lo, pvq_b, z);

    // vector quantizer (LDS-staged split-precision MFMA argmin + fused idx/SSE/hist)
    k_vqm<<<dim3(NROWS / 128), 256, 0, stream>>>(z, cbf_hi, cbf_lo, cb2, cbk,
                                                 idxv, counts, sse);

    // decoder
    k_dc1g<<<dim3(LQ / 64, 1, NB), 256, 0, stream>>>(idxv, cbk, wf_dc1, dc1_b, A);
    k_resblk<<<dim3(LQ / 64, 1, NB), 256, 0, stream>>>(A, Bb, wf_dr1, w2_dr1h, w2_dr1l);
    k_resblk<<<dim3(LQ / 64, 1, NB), 256, 0, stream>>>(Bb, A, wf_dr2, w2_dr2h, w2_dr2l);
    k_dt1m<<<dim3(LQ / 64, 1, NB), 256, 0, stream>>>(A, wf_dt1, dt1_b, Bb);
    k_dt2<<<dim3(L1 / 256, NB), 256, 0, stream>>>(Bb, dt2_w, dt2_b, out);

    // scalars
    k_final<<<dim3(1), 512, 0, stream>>>(counts, sse, out);
}

// Round 11
// 642.848 us; speedup vs baseline: 1.0112x; 1.0112x over previous
//
#include <hip/hip_runtime.h>
#include <math.h>

// Problem constants
static constexpr int NB  = 64;     // batch
static constexpr int L0  = 8192;   // input length
static constexpr int L1  = 4096;   // after ec1
static constexpr int LQ  = 2048;   // latent length
static constexpr int CH  = 128;    // hidden H
static constexpr int CHH = 64;     // H/2
static constexpr int CR  = 32;     // residual hidden
static constexpr int CD  = 64;     // codebook dim D
static constexpr int NK  = 512;    // codebook size K
static constexpr int NROWS = NB * LQ;  // 131072 latent vectors

using short8 = __attribute__((ext_vector_type(8))) short;
using f32x4  = __attribute__((ext_vector_type(4))) float;

__device__ inline f32x4 mfma16(short8 a, short8 b, f32x4 c) {
    return __builtin_amdgcn_mfma_f32_16x16x32_bf16(a, b, c, 0, 0, 0);
}

__device__ inline unsigned short bf16rne(float v) {
    unsigned int bb = __builtin_bit_cast(unsigned int, v);
    unsigned int r = (bb + 0x7FFFu + ((bb >> 16) & 1u)) >> 16;
    return (unsigned short)r;
}
__device__ inline float bf2f(unsigned short s) {
    unsigned int u = ((unsigned int)s) << 16;
    return __builtin_bit_cast(float, u);
}

// ---- conv weight->fragment prep: dst [tap][cb][kb][cl*32+hi*8+j] bf16 ----
__global__ __launch_bounds__(256) void k_wtf(const float* __restrict__ src,
                                             short* __restrict__ dst,
                                             int CO, int CI, int K, int iok) {
    int i = blockIdx.x * 256 + threadIdx.x;
    int total = K * CO * CI;
    if (i >= total) return;
    int j  = i & 7;
    int hi = (i >> 3) & 3;
    int cl = (i >> 5) & 15;
    int rest = i >> 9;
    int CIb = CI >> 5, COb = CO >> 4;
    int kb = rest % CIb; rest /= CIb;
    int cb = rest % COb;
    int tap = rest / COb;
    int co = cb * 16 + cl, ci = kb * 32 + hi * 8 + j;
    float v = iok ? src[(ci * CO + co) * K + tap] : src[(co * CI + ci) * K + tap];
    dst[i] = (short)bf16rne(v);
}

// ---- k=1 weight frag prep with hi/lo split: CO=128, CI=32 ----
__global__ __launch_bounds__(256) void k_w2f(const float* __restrict__ src,
                                             short* __restrict__ hi_dst,
                                             short* __restrict__ lo_dst) {
    int i = blockIdx.x * 256 + threadIdx.x;   // 4096
    if (i >= CH * CR) return;
    int j  = i & 7;
    int hi = (i >> 3) & 3;
    int cl = (i >> 5) & 15;
    int cb = i >> 9;
    int co = cb * 16 + cl, ci = hi * 8 + j;
    float v = src[co * CR + ci];
    unsigned short h = bf16rne(v);
    hi_dst[i] = (short)h;
    lo_dst[i] = (short)bf16rne(v - bf2f(h));
}

// ---- pvq weight frag prep with hi/lo split: CO=64 (d), CI=128 ----
__global__ __launch_bounds__(256) void k_pwf(const float* __restrict__ src,
                                             short* __restrict__ hi_dst,
                                             short* __restrict__ lo_dst) {
    int i = blockIdx.x * 256 + threadIdx.x;   // 8192
    if (i >= CD * CH) return;
    int j  = i & 7;
    int hi = (i >> 3) & 3;
    int cl = (i >> 5) & 15;
    int rest = i >> 9;
    int kb = rest & 3, cb = rest >> 2;
    int d = cb * 16 + cl, ci = kb * 32 + hi * 8 + j;
    float v = src[d * CH + ci];
    unsigned short h = bf16rne(v);
    hi_dst[i] = (short)h;
    lo_dst[i] = (short)bf16rne(v - bf2f(h));
}

// ---- codebook A-frag prep, split precision: -2*cb = hi + lo (both bf16) ----
__global__ __launch_bounds__(256) void k_cbf(const float* __restrict__ cb,
                                             short* __restrict__ hi_dst,
                                             short* __restrict__ lo_dst) {
    int i = blockIdx.x * 256 + threadIdx.x;   // 32768
    if (i >= NK * CD) return;
    int j    = i & 7;
    int l    = (i >> 3) & 63;
    int half = (i >> 9) & 1;
    int mt   = i >> 10;
    int cl = l & 15, hi = l >> 4;
    int m = mt * 16 + cl;
    int k = half * 32 + hi * 8 + j;
    float v = -2.f * cb[m * CD + k];
    unsigned short h = bf16rne(v);
    float r = v - bf2f(h);
    hi_dst[i] = (short)h;
    lo_dst[i] = (short)bf16rne(r);
}

// ---------------- ec1: [B,1,8192] -> [B,64,4096], k4 s2 p1, bias+ReLU ----------------
__global__ __launch_bounds__(256) void k_ec1(const float* __restrict__ x,
                                             const float* __restrict__ w,
                                             const float* __restrict__ bias,
                                             float* __restrict__ out) {
    int n = blockIdx.x * 256 + threadIdx.x;
    int t  = n & (L1 - 1);
    int co = (n >> 12) & (CHH - 1);
    int b  = n >> 18;
    const float* xp = x + b * L0;
    float acc = bias[co];
    int p0 = 2 * t - 1;
#pragma unroll
    for (int k = 0; k < 4; ++k) {
        int p = p0 + k;
        if (p >= 0 && p < L0) acc += w[co * 4 + k] * xp[p];
    }
    out[n] = fmaxf(acc, 0.f);
}

// ---------------- MFMA conv v2: bf16 swizzled LDS [t][ci], ds_read_b128 B-frags -------
template <int CIN, int COUT, int NTAPS, int TSTRIDE, int SWS, int LIN,
          bool RELU_IN, bool TRANS_IN, bool HAS_BIAS, bool RELU_OUT>
__global__ __launch_bounds__(256) void k_mfconv2(const float* __restrict__ x,
                                                 const short* __restrict__ wf,
                                                 const float* __restrict__ bias,
                                                 float* __restrict__ out) {
    constexpr int XW = 63 * TSTRIDE + NTAPS;
    constexpr int MR = (COUT == 128) ? 4 : 1;
    constexpr int COb = COUT / 16, CIb = CIN / 32;
    __shared__ unsigned int xsu[CIN * XW / 2];
    int t0 = blockIdx.x * 64;
    int b  = blockIdx.z;
    int tid = threadIdx.x;

    if (TRANS_IN) {
        for (int i = tid; i < XW * (CIN / 2); i += 256) {
            int j = i / (CIN / 2);
            int ci = (i - j * (CIN / 2)) * 2;
            int p = t0 - 1 + j;
            float vx = 0.f, vy = 0.f;
            if (p >= 0 && p < LIN) {
                const float* s = x + ((size_t)b * LIN + p) * CIN + ci;
                vx = s[0]; vy = s[1];
            }
            if (RELU_IN) { vx = fmaxf(vx, 0.f); vy = fmaxf(vy, 0.f); }
            unsigned int u = (__builtin_bit_cast(unsigned int, vx) >> 16)
                           | (__builtin_bit_cast(unsigned int, vy) & 0xFFFF0000u);
            int byte = (j * CIN + ci) * 2;
            byte ^= ((j >> SWS) & 7) << 4;
            xsu[byte >> 2] = u;
        }
    } else {
        for (int i = tid; i < (CIN / 2) * XW; i += 256) {
            int ci2 = i / XW;
            int j = i - ci2 * XW;
            int ci = ci2 * 2;
            int p = t0 * TSTRIDE - 1 + j;
            float vx = 0.f, vy = 0.f;
            if (p >= 0 && p < LIN) {
                const float* s = x + ((size_t)b * CIN + ci) * LIN + p;
                vx = s[0]; vy = s[LIN];
            }
            if (RELU_IN) { vx = fmaxf(vx, 0.f); vy = fmaxf(vy, 0.f); }
            unsigned int u = (__builtin_bit_cast(unsigned int, vx) >> 16)
                           | (__builtin_bit_cast(unsigned int, vy) & 0xFFFF0000u);
            int byte = (j * CIN + ci) * 2;
            byte ^= ((j >> SWS) & 7) << 4;
            xsu[byte >> 2] = u;
        }
    }
    __syncthreads();

    int l  = tid & 63;
    int w  = tid >> 6;
    int cl = l & 15, hi = l >> 4;
    int co_w = (w & 1) * (MR * 16);
    int t_w  = (w >> 1) * 32;

    f32x4 acc[MR][2];
#pragma unroll
    for (int m = 0; m < MR; ++m)
#pragma unroll
        for (int n = 0; n < 2; ++n) acc[m][n] = (f32x4){0.f, 0.f, 0.f, 0.f};

#pragma unroll
    for (int tap = 0; tap < NTAPS; ++tap) {
#pragma unroll
        for (int kb = 0; kb < CIb; ++kb) {
            const short* ap = wf + ((size_t)((tap * COb + co_w / 16) * CIb + kb)) * 512
                            + cl * 32 + hi * 8;
            short8 a[MR];
#pragma unroll
            for (int m = 0; m < MR; ++m)
                a[m] = *reinterpret_cast<const short8*>(ap + (size_t)m * CIb * 512);
            short8 bf[2];
#pragma unroll
            for (int n = 0; n < 2; ++n) {
                int tt = (t_w + n * 16 + cl) * TSTRIDE + tap;
                int byte = (tt * CIN + kb * 32 + hi * 8) * 2;
                byte ^= ((tt >> SWS) & 7) << 4;
                bf[n] = *reinterpret_cast<const short8*>(
                            reinterpret_cast<const char*>(xsu) + byte);
            }
#pragma unroll
            for (int m = 0; m < MR; ++m)
#pragma unroll
                for (int n = 0; n < 2; ++n)
                    acc[m][n] = mfma16(a[m], bf[n], acc[m][n]);
        }
    }

#pragma unroll
    for (int m = 0; m < MR; ++m) {
#pragma unroll
        for (int n = 0; n < 2; ++n) {
#pragma unroll
            for (int r = 0; r < 4; ++r) {
                int co = co_w + m * 16 + hi * 4 + r;
                int t  = t0 + t_w + n * 16 + cl;
                float v = acc[m][n][r];
                if (HAS_BIAS) v += bias[co];
                if (RELU_OUT) v = fmaxf(v, 0.f);
                out[((size_t)b * COUT + co) * LQ + t] = v;
            }
        }
    }
}

// ---------------- dc1 with codebook gather: in = cb[idx[p]], k3 p1, bias ----------------
__global__ __launch_bounds__(256) void k_dc1g(const int* __restrict__ idx,
                                              const float* __restrict__ cb,
                                              const short* __restrict__ wf,
                                              const float* __restrict__ bias,
                                              float* __restrict__ out) {
    constexpr int XW = 66;
    __shared__ unsigned int xsu[CD * XW / 2];
    int t0 = blockIdx.x * 64;
    int b  = blockIdx.z;
    int tid = threadIdx.x;

    for (int i = tid; i < XW * (CD / 2); i += 256) {
        int j = i >> 5;                  // /(CD/2)=32
        int ci = (i & 31) * 2;
        int p = t0 - 1 + j;
        float vx = 0.f, vy = 0.f;
        if (p >= 0 && p < LQ) {
            int id = idx[(size_t)b * LQ + p];
            const float* s = cb + (size_t)id * CD + ci;
            vx = s[0]; vy = s[1];
        }
        unsigned int u = (__builtin_bit_cast(unsigned int, vx) >> 16)
                       | (__builtin_bit_cast(unsigned int, vy) & 0xFFFF0000u);
        int byte = (j * CD + ci) * 2;
        byte ^= (j & 7) << 4;
        xsu[byte >> 2] = u;
    }
    __syncthreads();

    int l  = tid & 63;
    int w  = tid >> 6;
    int cl = l & 15, hi = l >> 4;
    int co_w = (w & 1) * 64;
    int t_w  = (w >> 1) * 32;

    f32x4 acc[4][2];
#pragma unroll
    for (int m = 0; m < 4; ++m)
#pragma unroll
        for (int n = 0; n < 2; ++n) acc[m][n] = (f32x4){0.f, 0.f, 0.f, 0.f};

#pragma unroll
    for (int tap = 0; tap < 3; ++tap) {
#pragma unroll
        for (int kb = 0; kb < 2; ++kb) {
            const short* ap = wf + ((size_t)((tap * 8 + co_w / 16) * 2 + kb)) * 512
                            + cl * 32 + hi * 8;
            short8 a[4];
#pragma unroll
            for (int m = 0; m < 4; ++m)
                a[m] = *reinterpret_cast<const short8*>(ap + (size_t)m * 2 * 512);
            short8 bf[2];
#pragma unroll
            for (int n = 0; n < 2; ++n) {
                int tt = (t_w + n * 16 + cl) + tap;
                int byte = (tt * CD + kb * 32 + hi * 8) * 2;
                byte ^= (tt & 7) << 4;
                bf[n] = *reinterpret_cast<const short8*>(
                            reinterpret_cast<const char*>(xsu) + byte);
            }
#pragma unroll
            for (int m = 0; m < 4; ++m)
#pragma unroll
                for (int n = 0; n < 2; ++n)
                    acc[m][n] = mfma16(a[m], bf[n], acc[m][n]);
        }
    }

#pragma unroll
    for (int m = 0; m < 4; ++m) {
#pragma unroll
        for (int n = 0; n < 2; ++n) {
#pragma unroll
            for (int r = 0; r < 4; ++r) {
                int co = co_w + m * 16 + hi * 4 + r;
                int t  = t0 + t_w + n * 16 + cl;
                out[((size_t)b * CH + co) * LQ + t] = acc[m][n][r] + bias[co];
            }
        }
    }
}

// ---------------- fused residual block: dst = src + W2 . relu(conv3(relu(src))) --------
__global__ __launch_bounds__(256) void k_resblk(const float* __restrict__ src,
                                                float* __restrict__ dst,
                                                const short* __restrict__ wf1,
                                                const short* __restrict__ w2h,
                                                const short* __restrict__ w2l) {
    constexpr int XW = 66;
    __shared__ unsigned int xsu[CH * XW / 2];   // 16896 B
    __shared__ unsigned int hh[64 * 16];        // [t][ciu] hi, 4 KB
    __shared__ unsigned int hl[64 * 16];        // lo, 4 KB
    int t0 = blockIdx.x * 64;
    int b  = blockIdx.z;
    int tid = threadIdx.x;

    for (int i = tid; i < (CH / 2) * XW; i += 256) {
        int ci2 = i / XW;
        int j = i - ci2 * XW;
        int ci = ci2 * 2;
        int p = t0 - 1 + j;
        float vx = 0.f, vy = 0.f;
        if (p >= 0 && p < LQ) {
            const float* s = src + ((size_t)b * CH + ci) * LQ + p;
            vx = fmaxf(s[0], 0.f); vy = fmaxf(s[LQ], 0.f);
        }
        unsigned int u = (__builtin_bit_cast(unsigned int, vx) >> 16)
                       | (__builtin_bit_cast(unsigned int, vy) & 0xFFFF0000u);
        int byte = (j * CH + ci) * 2;
        byte ^= (j & 7) << 4;
        xsu[byte >> 2] = u;
    }
    __syncthreads();

    int l  = tid & 63;
    int w  = tid >> 6;
    int cl = l & 15, hi = l >> 4;
    int co_w1 = (w & 1) * 16;     // h-channel tile base (0 or 16)
    int t_w   = (w >> 1) * 32;    // t base (0..32)

    // ---- stage 1: h = conv3(relu(x)) ----
    f32x4 acc1[2];
    acc1[0] = (f32x4){0.f, 0.f, 0.f, 0.f};
    acc1[1] = (f32x4){0.f, 0.f, 0.f, 0.f};
#pragma unroll
    for (int tap = 0; tap < 3; ++tap) {
#pragma unroll
        for (int kb = 0; kb < 4; ++kb) {
            const short* ap = wf1 + ((size_t)((tap * 2 + (w & 1)) * 4 + kb)) * 512
                            + cl * 32 + hi * 8;
            short8 a = *reinterpret_cast<const short8*>(ap);
#pragma unroll
            for (int n = 0; n < 2; ++n) {
                int tt = (t_w + n * 16 + cl) + tap;
                int byte = (tt * CH + kb * 32 + hi * 8) * 2;
                byte ^= (tt & 7) << 4;
                short8 bf = *reinterpret_cast<const short8*>(
                                reinterpret_cast<const char*>(xsu) + byte);
                acc1[n] = mfma16(a, bf, acc1[n]);
            }
        }
    }

    // relu + hi/lo split -> h LDS [t][ciu] (u32 = 2 bf16), swizzle idx ^= (t&3)<<2
#pragma unroll
    for (int n = 0; n < 2; ++n) {
        int t = t_w + n * 16 + cl;
#pragma unroll
        for (int rp = 0; rp < 2; ++rp) {
            float v0 = fmaxf(acc1[n][2 * rp], 0.f);
            float v1 = fmaxf(acc1[n][2 * rp + 1], 0.f);
            unsigned short h0 = bf16rne(v0), h1 = bf16rne(v1);
            unsigned short l0 = bf16rne(v0 - bf2f(h0)), l1 = bf16rne(v1 - bf2f(h1));
            int ciu = (co_w1 >> 1) + hi * 2 + rp;
            int idx = t * 16 + (ciu ^ ((t & 3) << 2));
            hh[idx] = (unsigned int)h0 | ((unsigned int)h1 << 16);
            hl[idx] = (unsigned int)l0 | ((unsigned int)l1 << 16);
        }
    }
    __syncthreads();

    // ---- stage 2: res = W2 . relu(h), split precision; dst = src + res ----
    int co2_w = (w & 1) * 64;
    short8 bh[2], bl[2];
#pragma unroll
    for (int n2 = 0; n2 < 2; ++n2) {
        int t = t_w + n2 * 16 + cl;
        int idx = t * 16 + ((hi * 4) ^ ((t & 3) << 2));
        bh[n2] = *reinterpret_cast<const short8*>(&hh[idx]);
        bl[n2] = *reinterpret_cast<const short8*>(&hl[idx]);
    }
#pragma unroll
    for (int m2 = 0; m2 < 4; ++m2) {
        int co2 = co2_w + m2 * 16;
        const short* aph = w2h + (co2 / 16) * 512 + cl * 32 + hi * 8;
        const short* apl = w2l + (co2 / 16) * 512 + cl * 32 + hi * 8;
        short8 ah = *reinterpret_cast<const short8*>(aph);
        short8 al = *reinterpret_cast<const short8*>(apl);
#pragma unroll
        for (int n2 = 0; n2 < 2; ++n2) {
            f32x4 acc = (f32x4){0.f, 0.f, 0.f, 0.f};
            acc = mfma16(ah, bl[n2], acc);
            acc = mfma16(al, bh[n2], acc);
            acc = mfma16(ah, bh[n2], acc);
            int t = t0 + t_w + n2 * 16 + cl;
#pragma unroll
            for (int r = 0; r < 4; ++r) {
                int co = co2 + hi * 4 + r;
                size_t off = ((size_t)b * CH + co) * LQ + t;
                dst[off] = src[off] + acc[r];
            }
        }
    }
}

// ---------------- dt1 MFMA v2: ConvT 128->64 k4 s2 p1, relu(in), relu(out) -------------
__global__ __launch_bounds__(256) void k_dt1m(const float* __restrict__ x,
                                              const short* __restrict__ wf,  // IOK frags
                                              const float* __restrict__ bias,
                                              float* __restrict__ out) {
    constexpr int XW = 66;
    __shared__ unsigned int xsu[CH * XW / 2];
    int t0 = blockIdx.x * 64;     // u-range base
    int b  = blockIdx.z;
    int tid = threadIdx.x;
    for (int i = tid; i < (CH / 2) * XW; i += 256) {
        int ci2 = i / XW;
        int j = i - ci2 * XW;
        int ci = ci2 * 2;
        int p = t0 - 1 + j;
        float vx = 0.f, vy = 0.f;
        if (p >= 0 && p < LQ) {
            const float* s = x + ((size_t)b * CH + ci) * LQ + p;
            vx = fmaxf(s[0], 0.f); vy = fmaxf(s[LQ], 0.f);
        }
        unsigned int u = (__builtin_bit_cast(unsigned int, vx) >> 16)
                       | (__builtin_bit_cast(unsigned int, vy) & 0xFFFF0000u);
        int byte = (j * CH + ci) * 2;
        byte ^= (j & 7) << 4;
        xsu[byte >> 2] = u;
    }
    __syncthreads();

    int l  = tid & 63;
    int w  = tid >> 6;
    int cl = l & 15, hi = l >> 4;
    int co_w = (w & 1) * 32;
    int u_w  = (w >> 1) * 32;

    f32x4 ae[2][2], ao[2][2];
#pragma unroll
    for (int m = 0; m < 2; ++m)
#pragma unroll
        for (int n = 0; n < 2; ++n) {
            ae[m][n] = (f32x4){0.f, 0.f, 0.f, 0.f};
            ao[m][n] = (f32x4){0.f, 0.f, 0.f, 0.f};
        }

    const int TK[4] = {1, 3, 0, 2};
    const int TO[4] = {1, 0, 2, 1};
#pragma unroll
    for (int te = 0; te < 4; ++te) {
        int k = TK[te], off = TO[te];
#pragma unroll
        for (int kb = 0; kb < 4; ++kb) {
            const short* ap = wf + (size_t)((k * 4 + co_w / 16) * 4 + kb) * 512
                            + cl * 32 + hi * 8;
            short8 a[2];
#pragma unroll
            for (int m = 0; m < 2; ++m)
                a[m] = *reinterpret_cast<const short8*>(ap + (size_t)m * 4 * 512);
            short8 bf[2];
#pragma unroll
            for (int n = 0; n < 2; ++n) {
                int tt = u_w + n * 16 + cl + off;
                int byte = (tt * CH + kb * 32 + hi * 8) * 2;
                byte ^= (tt & 7) << 4;
                bf[n] = *reinterpret_cast<const short8*>(
                            reinterpret_cast<const char*>(xsu) + byte);
            }
#pragma unroll
            for (int m = 0; m < 2; ++m)
#pragma unroll
                for (int n = 0; n < 2; ++n) {
                    if (te < 2) ae[m][n] = mfma16(a[m], bf[n], ae[m][n]);
                    else        ao[m][n] = mfma16(a[m], bf[n], ao[m][n]);
                }
        }
    }

#pragma unroll
    for (int m = 0; m < 2; ++m) {
#pragma unroll
        for (int n = 0; n < 2; ++n) {
#pragma unroll
            for (int r = 0; r < 4; ++r) {
                int co = co_w + m * 16 + hi * 4 + r;
                int u  = t0 + u_w + n * 16 + cl;
                float bv = bias[co];
                float2 rr;
                rr.x = fmaxf(ae[m][n][r] + bv, 0.f);
                rr.y = fmaxf(ao[m][n][r] + bv, 0.f);
                *reinterpret_cast<float2*>(&out[((size_t)b * CHH + co) * L1 + 2 * u]) = rr;
            }
        }
    }
}

// ---------------- pvq via split-precision MFMA: z[b,t,d], fp32-accurate ----------------
__global__ __launch_bounds__(256) void k_pvqm(const float* __restrict__ x,
                                              const short* __restrict__ pwh,
                                              const short* __restrict__ pwl,
                                              const float* __restrict__ bias,
                                              float* __restrict__ z) {
    __shared__ unsigned int xh[(CH / 2) * 64];   // 16 KB
    __shared__ unsigned int xl[(CH / 2) * 64];   // 16 KB
    int t0 = blockIdx.x * 64;
    int b  = blockIdx.y;
    int tid = threadIdx.x;

    for (int i = tid; i < (CH / 2) * 64; i += 256) {
        int ci2 = i >> 6;
        int t = i & 63;
        int ci = ci2 * 2;
        const float* s = x + ((size_t)b * CH + ci) * LQ + t0 + t;
        float vx = fmaxf(s[0], 0.f);
        float vy = fmaxf(s[LQ], 0.f);
        unsigned short hx = bf16rne(vx), hy = bf16rne(vy);
        unsigned short lx = bf16rne(vx - bf2f(hx)), ly = bf16rne(vy - bf2f(hy));
        int byte = (t * CH + ci) * 2;
        byte ^= (t & 7) << 4;
        xh[byte >> 2] = (unsigned int)hx | ((unsigned int)hy << 16);
        xl[byte >> 2] = (unsigned int)lx | ((unsigned int)ly << 16);
    }
    __syncthreads();

    int l  = tid & 63;
    int w  = tid >> 6;                 // wave = d-tile (4 x 16 = 64 d)
    int cl = l & 15, hi = l >> 4;

    float4 bv4 = *reinterpret_cast<const float4*>(&bias[w * 16 + hi * 4]);
    f32x4 acc[4];
#pragma unroll
    for (int nt = 0; nt < 4; ++nt) acc[nt] = (f32x4){bv4.x, bv4.y, bv4.z, bv4.w};

#pragma unroll
    for (int kb = 0; kb < 4; ++kb) {
        const short* aph = pwh + ((size_t)(w * 4 + kb)) * 512 + cl * 32 + hi * 8;
        const short* apl = pwl + ((size_t)(w * 4 + kb)) * 512 + cl * 32 + hi * 8;
        short8 ah = *reinterpret_cast<const short8*>(aph);
        short8 al = *reinterpret_cast<const short8*>(apl);
#pragma unroll
        for (int nt = 0; nt < 4; ++nt) {
            int tt = nt * 16 + cl;
            int byte = (tt * CH + kb * 32 + hi * 8) * 2;
            byte ^= (tt & 7) << 4;
            short8 bhf = *reinterpret_cast<const short8*>(
                             reinterpret_cast<const char*>(xh) + byte);
            short8 blf = *reinterpret_cast<const short8*>(
                             reinterpret_cast<const char*>(xl) + byte);
            acc[nt] = mfma16(ah, blf, acc[nt]);
            acc[nt] = mfma16(al, bhf, acc[nt]);
            acc[nt] = mfma16(ah, bhf, acc[nt]);
        }
    }

#pragma unroll
    for (int nt = 0; nt < 4; ++nt) {
        int t = t0 + nt * 16 + cl;
        float4 o;
        o.x = acc[nt][0]; o.y = acc[nt][1]; o.z = acc[nt][2]; o.w = acc[nt][3];
        *reinterpret_cast<float4*>(&z[((size_t)b * LQ + t) * CD + w * 16 + hi * 4]) = o;
    }
}

// ---------------- cb2[k] = |codebook_k|^2 ----------------
__global__ __launch_bounds__(256) void k_cb2(const float* __restrict__ cb,
                                             float* __restrict__ cb2) {
    int k = blockIdx.x * 256 + threadIdx.x;
    if (k >= NK) return;
    const float* r = cb + k * CD;
    float s = 0.f;
#pragma unroll 8
    for (int i = 0; i < CD; ++i) s += r[i] * r[i];
    cb2[k] = s;
}

// ---------------- VQ v4: direct L2 codebook loads, 32 rows/wave, grid 1024 -------------
// scores = |c|^2 - 2 z.c, split precision; low VGPR + high TLP (no LDS staging).
__global__ __launch_bounds__(256) void k_vqm(const float* __restrict__ z,
                                             const short* __restrict__ cbf_hi,
                                             const short* __restrict__ cbf_lo,
                                             const float* __restrict__ cb2,
                                             const float* __restrict__ cb,
                                             int* __restrict__ idxout,
                                             int* __restrict__ counts,
                                             float* __restrict__ sse) {
    __shared__ float c2l[NK];         // 2 KB
    __shared__ int   hist[NK];        // 2 KB
    int tid = threadIdx.x;
    int l   = tid & 63;
    int w   = tid >> 6;
    int cl  = l & 15, hi = l >> 4;
    int wrow0 = blockIdx.x * 128 + w * 32;

    for (int i = tid; i < NK; i += 256) { c2l[i] = cb2[i]; hist[i] = 0; }
    __syncthreads();

    // load z fragments (2 row-tiles of 16), split hi/lo (RNE)
    short8 bh[2][2], bl[2][2];
#pragma unroll
    for (int nt = 0; nt < 2; ++nt) {
        int row = wrow0 + nt * 16 + cl;
        const float* zr = z + (size_t)row * CD;
#pragma unroll
        for (int half = 0; half < 2; ++half) {
            const float4* p4 = reinterpret_cast<const float4*>(zr + half * 32 + hi * 8);
            float4 v0 = p4[0], v1 = p4[1];
            float vs[8] = {v0.x, v0.y, v0.z, v0.w, v1.x, v1.y, v1.z, v1.w};
            short8 sh, sl;
#pragma unroll
            for (int j = 0; j < 8; ++j) {
                unsigned short h = bf16rne(vs[j]);
                float r = vs[j] - bf2f(h);
                sh[j] = (short)h;
                sl[j] = (short)bf16rne(r);
            }
            bh[nt][half] = sh;
            bl[nt][half] = sl;
        }
    }

    float bscore[2];
    int   bidx[2];
#pragma unroll
    for (int nt = 0; nt < 2; ++nt) { bscore[nt] = 1e30f; bidx[nt] = 0; }

#pragma unroll 4
    for (int mt = 0; mt < 32; ++mt) {
        short8 ah0 = *reinterpret_cast<const short8*>(cbf_hi + (mt * 2 + 0) * 512 + l * 8);
        short8 ah1 = *reinterpret_cast<const short8*>(cbf_hi + (mt * 2 + 1) * 512 + l * 8);
        short8 al0 = *reinterpret_cast<const short8*>(cbf_lo + (mt * 2 + 0) * 512 + l * 8);
        short8 al1 = *reinterpret_cast<const short8*>(cbf_lo + (mt * 2 + 1) * 512 + l * 8);
        float4 c2v = *reinterpret_cast<const float4*>(&c2l[mt * 16 + hi * 4]);
        f32x4 cin = (f32x4){c2v.x, c2v.y, c2v.z, c2v.w};
        int mbase = mt * 16 + hi * 4;
#pragma unroll
        for (int nt = 0; nt < 2; ++nt) {
            f32x4 acc = mfma16(al0, bh[nt][0], cin);    // A_lo . z_hi
            acc = mfma16(al1, bh[nt][1], acc);
            acc = mfma16(ah0, bl[nt][0], acc);          // A_hi . z_lo
            acc = mfma16(ah1, bl[nt][1], acc);
            acc = mfma16(ah0, bh[nt][0], acc);          // A_hi . z_hi
            acc = mfma16(ah1, bh[nt][1], acc);
#pragma unroll
            for (int r = 0; r < 4; ++r) {
                float s = acc[r];
                bool better = s < bscore[nt];
                bscore[nt] = better ? s : bscore[nt];
                bidx[nt]   = better ? (mbase + r) : bidx[nt];
            }
        }
    }

    // cross-lane argmin + fused epilogue (idx write, SSE, hist)
    float err = 0.f;
#pragma unroll
    for (int nt = 0; nt < 2; ++nt) {
        float s = bscore[nt];
        int   id = bidx[nt];
#pragma unroll
        for (int off = 16; off <= 32; off <<= 1) {
            float s2 = __shfl_xor(s, off);
            int   i2 = __shfl_xor(id, off);
            bool take = (s2 < s) || (s2 == s && i2 < id);
            s  = take ? s2 : s;
            id = take ? i2 : id;
        }
        int row = wrow0 + nt * 16 + cl;
        if (hi == 0) idxout[row] = id;
        const float4* cbr = reinterpret_cast<const float4*>(cb + (size_t)id * CD);
        float4 q0 = cbr[hi * 2];
        float4 q1 = cbr[hi * 2 + 1];
        float4 q2 = cbr[8 + hi * 2];
        float4 q3 = cbr[8 + hi * 2 + 1];
        float qv[16] = {q0.x, q0.y, q0.z, q0.w, q1.x, q1.y, q1.z, q1.w,
                        q2.x, q2.y, q2.z, q2.w, q3.x, q3.y, q3.z, q3.w};
#pragma unroll
        for (int half = 0; half < 2; ++half) {
#pragma unroll
            for (int j = 0; j < 8; ++j) {
                float zv = bf2f((unsigned short)bh[nt][half][j])
                         + bf2f((unsigned short)bl[nt][half][j]);
                float d = qv[half * 8 + j] - zv;
                err = fmaf(d, d, err);
            }
        }
        if (hi == 0) atomicAdd(&hist[id], 1);
    }
#pragma unroll
    for (int s = 32; s > 0; s >>= 1) err += __shfl_xor(err, s);
    if (l == 0) atomicAdd(sse, err);

    __syncthreads();
    for (int i = tid; i < NK; i += 256) {
        int h = hist[i];
        if (h) atomicAdd(&counts[i], h);
    }
}

// ---------------- dt2: ConvT 64->1 k4 s2 p1 -> recon ----------------
__global__ __launch_bounds__(256) void k_dt2(const float* __restrict__ x,
                                             const float* __restrict__ w,
                                             const float* __restrict__ bias,
                                             float* __restrict__ out) {
    int u = blockIdx.x * 256 + threadIdx.x;
    int b = blockIdx.y;
    const float* xp = x + (size_t)b * CHH * L1 + u;
    float bv = bias[0];
    float ae = bv, ao = bv;
    for (int ci = 0; ci < CHH; ++ci) {
        const float* xr = xp + ci * L1;
        float xm  = (u >= 1) ? xr[-1] : 0.f;
        float x0  = xr[0];
        float xp1 = (u < L1 - 1) ? xr[1] : 0.f;
        const float* wc = w + ci * 4;
        ae += wc[1] * x0 + wc[3] * xm;
        ao += wc[0] * xp1 + wc[2] * x0;
    }
    reinterpret_cast<float2*>(out + (size_t)b * L0)[u] = make_float2(ae, ao);
}

// ---------------- finalize: vq_loss + perplexity ----------------
__global__ __launch_bounds__(512) void k_final(const int* __restrict__ counts,
                                               const float* __restrict__ sse,
                                               float* __restrict__ out) {
    __shared__ float red[8];
    int tid = threadIdx.x;
    float p = (float)counts[tid] * (1.f / (float)NROWS);
    float v = p * logf(p + 1e-10f);
#pragma unroll
    for (int s = 32; s > 0; s >>= 1) v += __shfl_down(v, s);
    if ((tid & 63) == 0) red[tid >> 6] = v;
    __syncthreads();
    if (tid == 0) {
        float tot = 0.f;
        for (int i = 0; i < 8; ++i) tot += red[i];
        out[524288] = 1.25f * sse[0] / ((float)NROWS * (float)CD);
        out[524289] = expf(-tot);
    }
}

extern "C" void kernel_launch(void* const* d_in, const int* in_sizes, int n_in,
                              void* d_out, int out_size, void* d_ws, size_t ws_size,
                              hipStream_t stream) {
    const float* x      = (const float*)d_in[0];
    const float* ec1_w  = (const float*)d_in[1];
    const float* ec1_b  = (const float*)d_in[2];
    const float* ec2_w  = (const float*)d_in[3];
    const float* ec2_b  = (const float*)d_in[4];
    const float* ec3_w  = (const float*)d_in[5];
    const float* ec3_b  = (const float*)d_in[6];
    const float* er1_w1 = (const float*)d_in[7];
    const float* er1_w2 = (const float*)d_in[8];
    const float* er2_w1 = (const float*)d_in[9];
    const float* er2_w2 = (const float*)d_in[10];
    const float* pvq_w  = (const float*)d_in[11];
    const float* pvq_b  = (const float*)d_in[12];
    const float* cbk    = (const float*)d_in[13];
    const float* dc1_w  = (const float*)d_in[14];
    const float* dc1_b  = (const float*)d_in[15];
    const float* dr1_w1 = (const float*)d_in[16];
    const float* dr1_w2 = (const float*)d_in[17];
    const float* dr2_w1 = (const float*)d_in[18];
    const float* dr2_w2 = (const float*)d_in[19];
    const float* dt1_w  = (const float*)d_in[20];
    const float* dt1_b  = (const float*)d_in[21];
    const float* dt2_w  = (const float*)d_in[22];
    const float* dt2_b  = (const float*)d_in[23];
    float* out = (float*)d_out;

    char* ws = (char*)d_ws;
    float* A    = (float*)(ws);                        // 64 MB
    float* Bb   = (float*)(ws + 67108864);             // 64 MB
    char*  smal = ws + 134217728;
    int*   counts = (int*)smal;                        // 2048 B
    float* sse    = (float*)(smal + 2048);             // 4 B
    float* cb2    = (float*)(smal + 4096);             // 2048 B
    short* wf_ec2 = (short*)(smal + 8192);             // 32768 sh
    short* wf_ec3 = wf_ec2 + 32768;                    // 49152 sh
    short* wf_er1 = wf_ec3 + 49152;                    // 12288 sh
    short* wf_er2 = wf_er1 + 12288;
    short* wf_dc1 = wf_er2 + 12288;                    // 24576 sh
    short* wf_dr1 = wf_dc1 + 24576;
    short* wf_dr2 = wf_dr1 + 12288;
    short* wf_dt1 = wf_dr2 + 12288;                    // 32768 sh
    short* cbf_hi = wf_dt1 + 32768;                    // 32768 sh
    short* cbf_lo = cbf_hi + 32768;                    // 32768 sh
    short* w2_er1h = cbf_lo + 32768;                   // 4096 sh each
    short* w2_er1l = w2_er1h + 4096;
    short* w2_er2h = w2_er1l + 4096;
    short* w2_er2l = w2_er2h + 4096;
    short* w2_dr1h = w2_er2l + 4096;
    short* w2_dr1l = w2_dr1h + 4096;
    short* w2_dr2h = w2_dr1l + 4096;
    short* w2_dr2l = w2_dr2h + 4096;
    short* pw_hi   = w2_dr2l + 4096;                   // 8192 sh
    short* pw_lo   = pw_hi + 8192;                     // 8192 sh
    float* z = Bb;                                     // 32 MB  [B,2048,64]
    int*   idxv = (int*)((char*)Bb + 33554432);        // 512 KB (dead after dc1)

    hipMemsetAsync(smal, 0, 2056, stream);

    // weight / codebook fragment prep (tiny)
    k_wtf<<<dim3(128), 256, 0, stream>>>(ec2_w, wf_ec2, 128, 64, 4, 0);
    k_wtf<<<dim3(192), 256, 0, stream>>>(ec3_w, wf_ec3, 128, 128, 3, 0);
    k_wtf<<<dim3(48), 256, 0, stream>>>(er1_w1, wf_er1, 32, 128, 3, 0);
    k_wtf<<<dim3(48), 256, 0, stream>>>(er2_w1, wf_er2, 32, 128, 3, 0);
    k_wtf<<<dim3(96), 256, 0, stream>>>(dc1_w, wf_dc1, 128, 64, 3, 0);
    k_wtf<<<dim3(48), 256, 0, stream>>>(dr1_w1, wf_dr1, 32, 128, 3, 0);
    k_wtf<<<dim3(48), 256, 0, stream>>>(dr2_w1, wf_dr2, 32, 128, 3, 0);
    k_wtf<<<dim3(128), 256, 0, stream>>>(dt1_w, wf_dt1, 64, 128, 4, 1);
    k_w2f<<<dim3(16), 256, 0, stream>>>(er1_w2, w2_er1h, w2_er1l);
    k_w2f<<<dim3(16), 256, 0, stream>>>(er2_w2, w2_er2h, w2_er2l);
    k_w2f<<<dim3(16), 256, 0, stream>>>(dr1_w2, w2_dr1h, w2_dr1l);
    k_w2f<<<dim3(16), 256, 0, stream>>>(dr2_w2, w2_dr2h, w2_dr2l);
    k_pwf<<<dim3(32), 256, 0, stream>>>(pvq_w, pw_hi, pw_lo);
    k_cbf<<<dim3(128), 256, 0, stream>>>(cbk, cbf_hi, cbf_lo);
    k_cb2<<<dim3(2), 256, 0, stream>>>(cbk, cb2);

    // encoder
    k_ec1<<<dim3((NB * CHH * L1) / 256), 256, 0, stream>>>(x, ec1_w, ec1_b, A);
    k_mfconv2<64, 128, 4, 2, 1, L1, false, false, true, true>
        <<<dim3(LQ / 64, 1, NB), 256, 0, stream>>>(A, wf_ec2, ec2_b, Bb);
    k_mfconv2<128, 128, 3, 1, 0, LQ, false, false, true, false>
        <<<dim3(LQ / 64, 1, NB), 256, 0, stream>>>(Bb, wf_ec3, ec3_b, A);
    // fused residual blocks (ping-pong: halo read forbids in-place)
    k_resblk<<<dim3(LQ / 64, 1, NB), 256, 0, stream>>>(A, Bb, wf_er1, w2_er1h, w2_er1l);
    k_resblk<<<dim3(LQ / 64, 1, NB), 256, 0, stream>>>(Bb, A, wf_er2, w2_er2h, w2_er2l);
    k_pvqm<<<dim3(LQ / 64, NB), 256, 0, stream>>>(A, pw_hi, pw_lo, pvq_b, z);

    // vector quantizer (direct-load split-precision MFMA argmin + fused idx/SSE/hist)
    k_vqm<<<dim3(NROWS / 128), 256, 0, stream>>>(z, cbf_hi, cbf_lo, cb2, cbk,
                                                 idxv, counts, sse);

    // decoder
    k_dc1g<<<dim3(LQ / 64, 1, NB), 256, 0, stream>>>(idxv, cbk, wf_dc1, dc1_b, A);
    k_resblk<<<dim3(LQ / 64, 1, NB), 256, 0, stream>>>(A, Bb, wf_dr1, w2_dr1h, w2_dr1l);
    k_resblk<<<dim3(LQ / 64, 1, NB), 256, 0, stream>>>(Bb, A, wf_dr2, w2_dr2h, w2_dr2l);
    k_dt1m<<<dim3(LQ / 64, 1, NB), 256, 0, stream>>>(A, wf_dt1, dt1_b, Bb);
    k_dt2<<<dim3(L1 / 256, NB), 256, 0, stream>>>(Bb, dt2_w, dt2_b, out);

    // scalars
    k_final<<<dim3(1), 512, 0, stream>>>(counts, sse, out);
}